// Round 3
// baseline (3250.606 us; speedup 1.0000x reference)
//
#include <hip/hip_runtime.h>

#define N_NODESC 50000
#define N_EDGESC 600000
#define DIM 128
#define N_LAYERS 4
#define N_GRAPHS 128
#define BN_EPSF 1e-5f
#define NBLK 782          // ceil(N_NODESC / 64) for mlp
#define RED_ROWS 25       // ceil(NBLK / 32)
#define GCHUNK 128        // dst nodes per gather block
#define NCHUNK 391        // ceil(N_NODESC / GCHUNK)
#define NSLICE 8
#define SLICE_COLS 16

// ---------------- CSR build ----------------

__global__ void hist_kernel(const int* __restrict__ dst, int* __restrict__ deg) {
    int e = blockIdx.x * blockDim.x + threadIdx.x;
    if (e < N_EDGESC) atomicAdd(&deg[dst[e]], 1);
}

__global__ void scan_kernel(const int* __restrict__ deg, int* __restrict__ offs) {
    __shared__ int sdata[1024];
    __shared__ int s_carry;
    const int t = threadIdx.x;
    if (t == 0) s_carry = 0;
    __syncthreads();
    for (int base = 0; base < N_NODESC; base += 1024) {
        int i = base + t;
        int v = (i < N_NODESC) ? deg[i] : 0;
        sdata[t] = v;
        __syncthreads();
        int x = v;
        for (int o = 1; o < 1024; o <<= 1) {
            int y = (t >= o) ? sdata[t - o] : 0;
            __syncthreads();
            x += y;
            sdata[t] = x;
            __syncthreads();
        }
        int carry = s_carry;
        if (i < N_NODESC) offs[i] = carry + x - v;   // exclusive
        int total = sdata[1023];
        __syncthreads();
        if (t == 0) s_carry = carry + total;
        __syncthreads();
    }
    if (t == 0) offs[N_NODESC] = s_carry;
}

__global__ void fill_kernel(const int* __restrict__ src, const int* __restrict__ dst,
                            int* __restrict__ cursor, int* __restrict__ csr) {
    int e = blockIdx.x * blockDim.x + threadIdx.x;
    if (e < N_EDGESC) {
        int p = atomicAdd(&cursor[dst[e]], 1);
        csr[p] = src[e];
    }
}

// ---------------- graph boundaries (batch is sorted) ----------------

__global__ void ginit_kernel(int* __restrict__ gstart) {
    int i = threadIdx.x;
    if (i <= N_GRAPHS) gstart[i] = N_NODESC;
}

__global__ void gbound_kernel(const int* __restrict__ batch, int* __restrict__ gstart) {
    int i = blockIdx.x * blockDim.x + threadIdx.x;
    if (i >= N_NODESC) return;
    int b = batch[i];
    int bp = (i == 0) ? -1 : batch[i - 1];
    for (int g = bp + 1; g <= b; ++g) gstart[g] = i;
}

// ---------------- helpers ----------------

__device__ __forceinline__ float4 bnrelu4(float4 v, float4 a, float4 b) {
    float4 r;
    r.x = fmaxf(fmaf(v.x, a.x, b.x), 0.f);
    r.y = fmaxf(fmaf(v.y, a.y, b.y), 0.f);
    r.z = fmaxf(fmaf(v.z, a.z, b.z), 0.f);
    r.w = fmaxf(fmaf(v.w, a.w, b.w), 0.f);
    return r;
}

// ---------------- sliced gather: agg[n, cols] = bnrelu(h[n]) + sum bnrelu(h[src]) ----------------
// slice = blockIdx % 8 -> lands on one XCD (round-robin dispatch); per-XCD working set =
// 50000 x 16 cols x 4B = 3.2 MB, L2-resident. One edge read = 64B = one cache line.
// 256 threads = 16 groups of 16 lanes; group owns dst nodes grp, grp+16, ...

template <int APPLY>
__global__ __launch_bounds__(256) void gather_sliced(const float* __restrict__ hin,
                                                     const float* __restrict__ ab,
                                                     const int* __restrict__ offs,
                                                     const int* __restrict__ csr,
                                                     float* __restrict__ agg) {
    const int slice = blockIdx.x & (NSLICE - 1);
    const int chunk = blockIdx.x >> 3;
    const int t = threadIdx.x;
    const int lane16 = t & 15;
    const int grp = t >> 4;
    const int col = slice * SLICE_COLS + lane16;
    float a = 1.f, b = 0.f;
    if (APPLY) { a = ab[col]; b = ab[DIM + col]; }
    const int nbase = chunk * GCHUNK;
    for (int m = grp; m < GCHUNK; m += 16) {
        int node = nbase + m;
        if (node >= N_NODESC) break;
        float v = hin[(size_t)node * DIM + col];
        float acc = APPLY ? fmaxf(fmaf(v, a, b), 0.f) : v;
        const int e1 = offs[node + 1];
        for (int e = offs[node]; e < e1; ++e) {
            int s = csr[e];
            float w = hin[(size_t)s * DIM + col];
            acc += APPLY ? fmaxf(fmaf(w, a, b), 0.f) : w;
        }
        agg[(size_t)node * DIM + col] = acc;
    }
}

// ---------------- MLP: z = relu(agg@W1+b1)@W2+b2, + BN partials (block-reduced) ----------------
// block = 256 threads, 64 nodes/block. j4 = (t&31)*4 cols, m0 = (t>>5)*8 rows.

__global__ __launch_bounds__(256, 3) void mlp_kernel(const float* __restrict__ in,
                                                     const float* __restrict__ W1,
                                                     const float* __restrict__ b1,
                                                     const float* __restrict__ W2,
                                                     const float* __restrict__ b2,
                                                     float* __restrict__ zout,
                                                     float* __restrict__ partials) {
    __shared__ float inT[64][DIM];
    __shared__ float wch[32][DIM];
    const int t = threadIdx.x;
    const int j4 = (t & 31) << 2;
    const int m0 = (t >> 5) << 3;
    const int nodeBase = blockIdx.x * 64;

    // stage 64 input rows
    for (int p = 0; p < 8; ++p) {
        int idx = p * 256 + t;
        int row = idx >> 5, k4 = (idx & 31) << 2;
        int node = nodeBase + row;
        float4 v = make_float4(0.f, 0.f, 0.f, 0.f);
        if (node < N_NODESC) v = *(const float4*)(in + (size_t)node * DIM + k4);
        *(float4*)&inT[row][k4] = v;
    }

    float acc[8][4];
#pragma unroll
    for (int m = 0; m < 8; ++m)
#pragma unroll
        for (int jj = 0; jj < 4; ++jj) acc[m][jj] = 0.f;

    // ---- GEMM1 ----
    for (int kc = 0; kc < 4; ++kc) {
        __syncthreads();
        for (int p = 0; p < 4; ++p) {
            int idx = p * 256 + t;
            int r = idx >> 5, cc = (idx & 31) << 2;
            *(float4*)&wch[r][cc] = *(const float4*)(W1 + (size_t)(kc * 32 + r) * DIM + cc);
        }
        __syncthreads();
#pragma unroll
        for (int k = 0; k < 32; k += 4) {
            float4 w0 = *(float4*)&wch[k + 0][j4];
            float4 w1 = *(float4*)&wch[k + 1][j4];
            float4 w2v = *(float4*)&wch[k + 2][j4];
            float4 w3 = *(float4*)&wch[k + 3][j4];
#pragma unroll
            for (int m = 0; m < 8; ++m) {
                float4 iv = *(float4*)&inT[m0 + m][kc * 32 + k];
                acc[m][0] += iv.x * w0.x + iv.y * w1.x + iv.z * w2v.x + iv.w * w3.x;
                acc[m][1] += iv.x * w0.y + iv.y * w1.y + iv.z * w2v.y + iv.w * w3.y;
                acc[m][2] += iv.x * w0.z + iv.y * w1.z + iv.z * w2v.z + iv.w * w3.z;
                acc[m][3] += iv.x * w0.w + iv.y * w1.w + iv.z * w2v.w + iv.w * w3.w;
            }
        }
    }

    // bias + relu -> mid into inT
    {
        float4 bb = *(const float4*)(b1 + j4);
        __syncthreads();
#pragma unroll
        for (int m = 0; m < 8; ++m) {
            float4 v;
            v.x = fmaxf(acc[m][0] + bb.x, 0.f);
            v.y = fmaxf(acc[m][1] + bb.y, 0.f);
            v.z = fmaxf(acc[m][2] + bb.z, 0.f);
            v.w = fmaxf(acc[m][3] + bb.w, 0.f);
            *(float4*)&inT[m0 + m][j4] = v;
            acc[m][0] = acc[m][1] = acc[m][2] = acc[m][3] = 0.f;
        }
    }

    // ---- GEMM2 ----
    for (int kc = 0; kc < 4; ++kc) {
        __syncthreads();
        for (int p = 0; p < 4; ++p) {
            int idx = p * 256 + t;
            int r = idx >> 5, cc = (idx & 31) << 2;
            *(float4*)&wch[r][cc] = *(const float4*)(W2 + (size_t)(kc * 32 + r) * DIM + cc);
        }
        __syncthreads();
#pragma unroll
        for (int k = 0; k < 32; k += 4) {
            float4 w0 = *(float4*)&wch[k + 0][j4];
            float4 w1 = *(float4*)&wch[k + 1][j4];
            float4 w2v = *(float4*)&wch[k + 2][j4];
            float4 w3 = *(float4*)&wch[k + 3][j4];
#pragma unroll
            for (int m = 0; m < 8; ++m) {
                float4 iv = *(float4*)&inT[m0 + m][kc * 32 + k];
                acc[m][0] += iv.x * w0.x + iv.y * w1.x + iv.z * w2v.x + iv.w * w3.x;
                acc[m][1] += iv.x * w0.y + iv.y * w1.y + iv.z * w2v.y + iv.w * w3.y;
                acc[m][2] += iv.x * w0.z + iv.y * w1.z + iv.z * w2v.z + iv.w * w3.z;
                acc[m][3] += iv.x * w0.w + iv.y * w1.w + iv.z * w2v.w + iv.w * w3.w;
            }
        }
    }

    // bias, store z, block-reduce BN partials
    float4 b2v = *(const float4*)(b2 + j4);
    float s1[4] = {0.f, 0.f, 0.f, 0.f};
    float s2[4] = {0.f, 0.f, 0.f, 0.f};
#pragma unroll
    for (int m = 0; m < 8; ++m) {
        int node = nodeBase + m0 + m;
        if (node < N_NODESC) {
            float4 z;
            z.x = acc[m][0] + b2v.x;
            z.y = acc[m][1] + b2v.y;
            z.z = acc[m][2] + b2v.z;
            z.w = acc[m][3] + b2v.w;
            *(float4*)(zout + (size_t)node * DIM + j4) = z;
            s1[0] += z.x; s2[0] += z.x * z.x;
            s1[1] += z.y; s2[1] += z.y * z.y;
            s1[2] += z.z; s2[2] += z.z * z.z;
            s1[3] += z.w; s2[3] += z.w * z.w;
        }
    }
    __syncthreads();
    float* red = (float*)wch;
    *(float4*)&red[t * 8 + 0] = make_float4(s1[0], s1[1], s1[2], s1[3]);
    *(float4*)&red[t * 8 + 4] = make_float4(s2[0], s2[1], s2[2], s2[3]);
    __syncthreads();
    if (t < 32) {
        float4 S1 = make_float4(0.f, 0.f, 0.f, 0.f);
        float4 S2 = make_float4(0.f, 0.f, 0.f, 0.f);
#pragma unroll
        for (int g = 0; g < 8; ++g) {
            float4 u1 = *(float4*)&red[((g << 5) | t) * 8 + 0];
            float4 u2 = *(float4*)&red[((g << 5) | t) * 8 + 4];
            S1.x += u1.x; S1.y += u1.y; S1.z += u1.z; S1.w += u1.w;
            S2.x += u2.x; S2.y += u2.y; S2.z += u2.z; S2.w += u2.w;
        }
        *(float4*)(partials + (size_t)blockIdx.x * 256 + t * 4) = S1;
        *(float4*)(partials + (size_t)blockIdx.x * 256 + DIM + t * 4) = S2;
    }
}

// ---------------- stats reduce + BN finalize ----------------

__global__ __launch_bounds__(256) void reduce_stats(const float* __restrict__ partials,
                                                    float* __restrict__ stats) {
    int c = threadIdx.x;
    int r0 = blockIdx.x * RED_ROWS;
    int r1 = r0 + RED_ROWS;
    if (r1 > NBLK) r1 = NBLK;
    float s = 0.f;
    for (int r = r0; r < r1; ++r) s += partials[(size_t)r * 256 + c];
    atomicAdd(&stats[c], s);
}

__global__ void bn_finalize(const float* __restrict__ stats, const float* __restrict__ gamma,
                            const float* __restrict__ beta, float* __restrict__ ab) {
    int j = threadIdx.x;
    float s1 = stats[j], s2 = stats[DIM + j];
    const float invN = 1.0f / (float)N_NODESC;
    float mean = s1 * invN;
    float var = s2 * invN - mean * mean;
    float a = gamma[j] * rsqrtf(var + BN_EPSF);
    float b = beta[j] - mean * a;
    ab[j] = a;
    ab[DIM + j] = b;
}

// ---------------- global mean pool (applies last-layer BN+ReLU) ----------------

__global__ __launch_bounds__(256) void pool_kernel(const float* __restrict__ z,
                                                   const int* __restrict__ gstart,
                                                   const float* __restrict__ ab,
                                                   float* __restrict__ outp) {
    __shared__ float sred[8][DIM];
    const int g = blockIdx.x;
    const int lane = threadIdx.x & 31;
    const int grp = threadIdx.x >> 5;
    const int c4 = lane << 2;
    const int ns = gstart[g], ne = gstart[g + 1];
    float4 a4 = *(const float4*)(ab + c4);
    float4 b4 = *(const float4*)(ab + DIM + c4);
    float4 acc = make_float4(0.f, 0.f, 0.f, 0.f);
    for (int m = ns + grp; m < ne; m += 8) {
        float4 v = *(const float4*)(z + (size_t)m * DIM + c4);
        v = bnrelu4(v, a4, b4);
        acc.x += v.x; acc.y += v.y; acc.z += v.z; acc.w += v.w;
    }
    *(float4*)&sred[grp][c4] = acc;
    __syncthreads();
    if (grp == 0) {
#pragma unroll
        for (int q = 1; q < 8; ++q) {
            float4 u = *(float4*)&sred[q][c4];
            acc.x += u.x; acc.y += u.y; acc.z += u.z; acc.w += u.w;
        }
        float inv = 1.0f / fmaxf((float)(ne - ns), 1.0f);
        float4 o = make_float4(acc.x * inv, acc.y * inv, acc.z * inv, acc.w * inv);
        *(float4*)(outp + (size_t)g * DIM + c4) = o;
    }
}

// ---------------- launcher ----------------

extern "C" void kernel_launch(void* const* d_in, const int* in_sizes, int n_in,
                              void* d_out, int out_size, void* d_ws, size_t ws_size,
                              hipStream_t stream) {
    const float* x     = (const float*)d_in[0];
    const int*   ei    = (const int*)d_in[1];
    const int*   batch = (const int*)d_in[2];
    const float* W1    = (const float*)d_in[3];
    const float* b1    = (const float*)d_in[4];
    const float* W2    = (const float*)d_in[5];
    const float* b2    = (const float*)d_in[6];
    const float* gamma = (const float*)d_in[7];
    const float* beta  = (const float*)d_in[8];
    float* out = (float*)d_out;

    char* ws = (char*)d_ws;
    size_t off = 0;
    auto alloc = [&](size_t bytes) -> void* {
        void* p = ws + off;
        off += (bytes + 255) & ~(size_t)255;
        return p;
    };
    int*   deg      = (int*)alloc((size_t)N_NODESC * 4);
    int*   offs     = (int*)alloc((size_t)(N_NODESC + 1) * 4);
    int*   cursor   = (int*)alloc((size_t)N_NODESC * 4);
    int*   csr      = (int*)alloc((size_t)N_EDGESC * 4);
    int*   gstart   = (int*)alloc((size_t)(N_GRAPHS + 1) * 4);
    float* stats    = (float*)alloc(256 * 4);
    float* ab       = (float*)alloc(256 * 4);
    float* partials = (float*)alloc((size_t)NBLK * 256 * 4);
    float* bufAgg   = (float*)alloc((size_t)N_NODESC * DIM * 4);
    float* bufZ0    = (float*)alloc((size_t)N_NODESC * DIM * 4);
    float* bufZ1    = (float*)alloc((size_t)N_NODESC * DIM * 4);

    const int* srcp = ei;
    const int* dstp = ei + N_EDGESC;

    // CSR build
    hipMemsetAsync(deg, 0, (size_t)N_NODESC * 4, stream);
    hist_kernel<<<(N_EDGESC + 255) / 256, 256, 0, stream>>>(dstp, deg);
    scan_kernel<<<1, 1024, 0, stream>>>(deg, offs);
    hipMemcpyAsync(cursor, offs, (size_t)N_NODESC * 4, hipMemcpyDeviceToDevice, stream);
    fill_kernel<<<(N_EDGESC + 255) / 256, 256, 0, stream>>>(srcp, dstp, cursor, csr);

    // graph boundaries
    ginit_kernel<<<1, 256, 0, stream>>>(gstart);
    gbound_kernel<<<(N_NODESC + 255) / 256, 256, 0, stream>>>(batch, gstart);

    const float* hin = x;
    float* zbufs[2] = {bufZ0, bufZ1};
    for (int l = 0; l < N_LAYERS; ++l) {
        float* zout = zbufs[l & 1];
        const float* W1l = W1 + (size_t)l * DIM * DIM;
        const float* b1l = b1 + (size_t)l * DIM;
        const float* W2l = W2 + (size_t)l * DIM * DIM;
        const float* b2l = b2 + (size_t)l * DIM;
        if (l == 0)
            gather_sliced<0><<<NCHUNK * NSLICE, 256, 0, stream>>>(hin, nullptr, offs, csr, bufAgg);
        else
            gather_sliced<1><<<NCHUNK * NSLICE, 256, 0, stream>>>(hin, ab, offs, csr, bufAgg);
        mlp_kernel<<<NBLK, 256, 0, stream>>>(bufAgg, W1l, b1l, W2l, b2l, zout, partials);
        hipMemsetAsync(stats, 0, 256 * 4, stream);
        reduce_stats<<<32, 256, 0, stream>>>(partials, stats);
        bn_finalize<<<1, DIM, 0, stream>>>(stats, gamma + (size_t)l * DIM, beta + (size_t)l * DIM, ab);
        hin = zout;
    }

    pool_kernel<<<N_GRAPHS, 256, 0, stream>>>(hin, gstart, ab, out);
}

// Round 11
// 1192.266 us; speedup vs baseline: 2.7264x; 2.7264x over previous
//
#include <hip/hip_runtime.h>

#define N_NODESC 50000
#define N_EDGESC 600000
#define DIM 128
#define N_LAYERS 4
#define N_GRAPHS 128
#define BN_EPSF 1e-5f

// persistent MLP config
#define MLP_GRID 256
#define MLP_TPB 512
#define TROWS 32
#define NTILES ((N_NODESC + TROWS - 1) / TROWS)        // 1563
#define MLP_LDS_FLOATS (16384 + 16384 + TROWS * DIM)   // 36864 floats = 144 KiB
// stats reduce
#define RED_ROWS 8                                     // 256 partial rows / 32 blocks

// gather config
#define GCHUNK 128
#define NCHUNK 391        // ceil(N_NODESC / GCHUNK)
#define NSLICE 8
#define SLICE_COLS 16

// ---------------- CSR build ----------------

__global__ void hist_kernel(const int* __restrict__ dst, int* __restrict__ deg) {
    int e = blockIdx.x * blockDim.x + threadIdx.x;
    if (e < N_EDGESC) atomicAdd(&deg[dst[e]], 1);
}

__global__ void scan_kernel(const int* __restrict__ deg, int* __restrict__ offs) {
    __shared__ int sdata[1024];
    __shared__ int s_carry;
    const int t = threadIdx.x;
    if (t == 0) s_carry = 0;
    __syncthreads();
    for (int base = 0; base < N_NODESC; base += 1024) {
        int i = base + t;
        int v = (i < N_NODESC) ? deg[i] : 0;
        sdata[t] = v;
        __syncthreads();
        int x = v;
        for (int o = 1; o < 1024; o <<= 1) {
            int y = (t >= o) ? sdata[t - o] : 0;
            __syncthreads();
            x += y;
            sdata[t] = x;
            __syncthreads();
        }
        int carry = s_carry;
        if (i < N_NODESC) offs[i] = carry + x - v;   // exclusive
        int total = sdata[1023];
        __syncthreads();
        if (t == 0) s_carry = carry + total;
        __syncthreads();
    }
    if (t == 0) offs[N_NODESC] = s_carry;
}

__global__ void fill_kernel(const int* __restrict__ src, const int* __restrict__ dst,
                            int* __restrict__ cursor, int* __restrict__ csr) {
    int e = blockIdx.x * blockDim.x + threadIdx.x;
    if (e < N_EDGESC) {
        int p = atomicAdd(&cursor[dst[e]], 1);
        csr[p] = src[e];
    }
}

// ---------------- graph boundaries (batch is sorted) ----------------

__global__ void ginit_kernel(int* __restrict__ gstart) {
    int i = threadIdx.x;
    if (i <= N_GRAPHS) gstart[i] = N_NODESC;
}

__global__ void gbound_kernel(const int* __restrict__ batch, int* __restrict__ gstart) {
    int i = blockIdx.x * blockDim.x + threadIdx.x;
    if (i >= N_NODESC) return;
    int b = batch[i];
    int bp = (i == 0) ? -1 : batch[i - 1];
    for (int g = bp + 1; g <= b; ++g) gstart[g] = i;
}

// ---------------- helpers ----------------

__device__ __forceinline__ float4 bnrelu4(float4 v, float4 a, float4 b) {
    float4 r;
    r.x = fmaxf(fmaf(v.x, a.x, b.x), 0.f);
    r.y = fmaxf(fmaf(v.y, a.y, b.y), 0.f);
    r.z = fmaxf(fmaf(v.z, a.z, b.z), 0.f);
    r.w = fmaxf(fmaf(v.w, a.w, b.w), 0.f);
    return r;
}

// ---------------- sliced gather (L2-resident per-XCD column slice) ----------------

template <int APPLY>
__global__ __launch_bounds__(256) void gather_sliced(const float* __restrict__ hin,
                                                     const float* __restrict__ ab,
                                                     const int* __restrict__ offs,
                                                     const int* __restrict__ csr,
                                                     float* __restrict__ agg) {
    const int slice = blockIdx.x & (NSLICE - 1);
    const int chunk = blockIdx.x >> 3;
    const int t = threadIdx.x;
    const int lane16 = t & 15;
    const int grp = t >> 4;
    const int col = slice * SLICE_COLS + lane16;
    float a = 1.f, b = 0.f;
    if (APPLY) { a = ab[col]; b = ab[DIM + col]; }
    const int nbase = chunk * GCHUNK;
    for (int m = grp; m < GCHUNK; m += 16) {
        int node = nbase + m;
        if (node >= N_NODESC) break;
        float v = hin[(size_t)node * DIM + col];
        float acc = APPLY ? fmaxf(fmaf(v, a, b), 0.f) : v;
        const int e1 = offs[node + 1];
        for (int e = offs[node]; e < e1; ++e) {
            int s = csr[e];
            float w = hin[(size_t)s * DIM + col];
            acc += APPLY ? fmaxf(fmaf(w, a, b), 0.f) : w;
        }
        agg[(size_t)node * DIM + col] = acc;
    }
}

// ---------------- persistent weight-resident MLP ----------------
// 256 blocks (1/CU) x 512 threads (8 waves). W1+W2 staged to LDS ONCE (128 KiB),
// then grid-stride over 32-node tiles: stage tile (16 KiB), GEMM1 -> relu -> GEMM2
// entirely from LDS, store z + accumulate BN partials in registers.
// Thread t: cols j4 = (t&31)*4 .. +3, rows m0 = (t>>5)*2 .. +1.

__global__ __launch_bounds__(MLP_TPB, 2) void mlp_persist(const float* __restrict__ in,
                                                          const float* __restrict__ W1,
                                                          const float* __restrict__ b1,
                                                          const float* __restrict__ W2,
                                                          const float* __restrict__ b2,
                                                          float* __restrict__ zout,
                                                          float* __restrict__ partials) {
    extern __shared__ float lds[];
    float* W1s = lds;                    // [128][128]
    float* W2s = lds + 16384;            // [128][128]
    float* inT = lds + 32768;            // [32][128] (also mid, also reduce scratch)
    const int t = threadIdx.x;

    // stage both weight matrices once: 2 x 4096 float4, 8 each per thread
#pragma unroll
    for (int p = 0; p < 8; ++p) {
        int idx = (p * MLP_TPB + t) << 2;             // float offset, 16B aligned
        *(float4*)&W1s[idx] = *(const float4*)(W1 + idx);
        *(float4*)&W2s[idx] = *(const float4*)(W2 + idx);
    }

    const int lane = t & 31;
    const int j4 = lane << 2;
    const int m0 = (t >> 5) << 1;
    const float4 b1v = *(const float4*)(b1 + j4);
    const float4 b2v = *(const float4*)(b2 + j4);
    float s1[4] = {0.f, 0.f, 0.f, 0.f};
    float s2[4] = {0.f, 0.f, 0.f, 0.f};

    __syncthreads();

    for (int tile = blockIdx.x; tile < NTILES; tile += MLP_GRID) {
        const int nodeBase = tile * TROWS;

        // stage 32 input rows: 1024 float4, 2 per thread
#pragma unroll
        for (int p = 0; p < 2; ++p) {
            int idx = p * MLP_TPB + t;                // 0..1023
            int row = idx >> 5, cc = (idx & 31) << 2;
            int node = nodeBase + row;
            float4 v = make_float4(0.f, 0.f, 0.f, 0.f);
            if (node < N_NODESC) v = *(const float4*)(in + (size_t)node * DIM + cc);
            *(float4*)&inT[row * DIM + cc] = v;
        }
        __syncthreads();

        float acc[2][4];
#pragma unroll
        for (int m = 0; m < 2; ++m)
#pragma unroll
            for (int j = 0; j < 4; ++j) acc[m][j] = 0.f;

        // ---- GEMM1: acc = inT @ W1s ----
#pragma unroll 8
        for (int k = 0; k < DIM; k += 4) {
            float4 w0 = *(float4*)&W1s[(k + 0) * DIM + j4];
            float4 w1 = *(float4*)&W1s[(k + 1) * DIM + j4];
            float4 w2v = *(float4*)&W1s[(k + 2) * DIM + j4];
            float4 w3 = *(float4*)&W1s[(k + 3) * DIM + j4];
#pragma unroll
            for (int m = 0; m < 2; ++m) {
                float4 iv = *(float4*)&inT[(m0 + m) * DIM + k];
                acc[m][0] += iv.x * w0.x + iv.y * w1.x + iv.z * w2v.x + iv.w * w3.x;
                acc[m][1] += iv.x * w0.y + iv.y * w1.y + iv.z * w2v.y + iv.w * w3.y;
                acc[m][2] += iv.x * w0.z + iv.y * w1.z + iv.z * w2v.z + iv.w * w3.z;
                acc[m][3] += iv.x * w0.w + iv.y * w1.w + iv.z * w2v.w + iv.w * w3.w;
            }
        }
        __syncthreads();                               // all inT reads done

        // mid = relu(acc + b1) -> back into inT
#pragma unroll
        for (int m = 0; m < 2; ++m) {
            float4 v;
            v.x = fmaxf(acc[m][0] + b1v.x, 0.f);
            v.y = fmaxf(acc[m][1] + b1v.y, 0.f);
            v.z = fmaxf(acc[m][2] + b1v.z, 0.f);
            v.w = fmaxf(acc[m][3] + b1v.w, 0.f);
            *(float4*)&inT[(m0 + m) * DIM + j4] = v;
            acc[m][0] = acc[m][1] = acc[m][2] = acc[m][3] = 0.f;
        }
        __syncthreads();

        // ---- GEMM2: acc = mid @ W2s ----
#pragma unroll 8
        for (int k = 0; k < DIM; k += 4) {
            float4 w0 = *(float4*)&W2s[(k + 0) * DIM + j4];
            float4 w1 = *(float4*)&W2s[(k + 1) * DIM + j4];
            float4 w2v = *(float4*)&W2s[(k + 2) * DIM + j4];
            float4 w3 = *(float4*)&W2s[(k + 3) * DIM + j4];
#pragma unroll
            for (int m = 0; m < 2; ++m) {
                float4 iv = *(float4*)&inT[(m0 + m) * DIM + k];
                acc[m][0] += iv.x * w0.x + iv.y * w1.x + iv.z * w2v.x + iv.w * w3.x;
                acc[m][1] += iv.x * w0.y + iv.y * w1.y + iv.z * w2v.y + iv.w * w3.y;
                acc[m][2] += iv.x * w0.z + iv.y * w1.z + iv.z * w2v.z + iv.w * w3.z;
                acc[m][3] += iv.x * w0.w + iv.y * w1.w + iv.z * w2v.w + iv.w * w3.w;
            }
        }

        // epilogue: bias, store z, accumulate BN partials in registers
#pragma unroll
        for (int m = 0; m < 2; ++m) {
            int node = nodeBase + m0 + m;
            if (node < N_NODESC) {
                float4 z;
                z.x = acc[m][0] + b2v.x;
                z.y = acc[m][1] + b2v.y;
                z.z = acc[m][2] + b2v.z;
                z.w = acc[m][3] + b2v.w;
                *(float4*)(zout + (size_t)node * DIM + j4) = z;
                s1[0] += z.x; s2[0] += z.x * z.x;
                s1[1] += z.y; s2[1] += z.y * z.y;
                s1[2] += z.z; s2[2] += z.z * z.z;
                s1[3] += z.w; s2[3] += z.w * z.w;
            }
        }
        __syncthreads();                               // before next tile restages inT
    }

    // block-level reduction of BN partials via inT scratch (512 x 8 floats = 16 KiB)
    *(float4*)&inT[t * 8 + 0] = make_float4(s1[0], s1[1], s1[2], s1[3]);
    *(float4*)&inT[t * 8 + 4] = make_float4(s2[0], s2[1], s2[2], s2[3]);
    __syncthreads();
    if (t < 32) {
        float4 S1 = make_float4(0.f, 0.f, 0.f, 0.f);
        float4 S2 = make_float4(0.f, 0.f, 0.f, 0.f);
#pragma unroll
        for (int g = 0; g < 16; ++g) {
            float4 u1 = *(float4*)&inT[(g * 32 + t) * 8 + 0];
            float4 u2 = *(float4*)&inT[(g * 32 + t) * 8 + 4];
            S1.x += u1.x; S1.y += u1.y; S1.z += u1.z; S1.w += u1.w;
            S2.x += u2.x; S2.y += u2.y; S2.z += u2.z; S2.w += u2.w;
        }
        *(float4*)(partials + (size_t)blockIdx.x * 256 + t * 4) = S1;
        *(float4*)(partials + (size_t)blockIdx.x * 256 + DIM + t * 4) = S2;
    }
}

// ---------------- stats reduce + BN finalize ----------------

__global__ __launch_bounds__(256) void reduce_stats(const float* __restrict__ partials,
                                                    float* __restrict__ stats) {
    int c = threadIdx.x;
    int r0 = blockIdx.x * RED_ROWS;
    int r1 = r0 + RED_ROWS;
    if (r1 > MLP_GRID) r1 = MLP_GRID;
    float s = 0.f;
    for (int r = r0; r < r1; ++r) s += partials[(size_t)r * 256 + c];
    atomicAdd(&stats[c], s);
}

__global__ void bn_finalize(const float* __restrict__ stats, const float* __restrict__ gamma,
                            const float* __restrict__ beta, float* __restrict__ ab) {
    int j = threadIdx.x;
    float s1 = stats[j], s2 = stats[DIM + j];
    const float invN = 1.0f / (float)N_NODESC;
    float mean = s1 * invN;
    float var = s2 * invN - mean * mean;
    float a = gamma[j] * rsqrtf(var + BN_EPSF);
    float b = beta[j] - mean * a;
    ab[j] = a;
    ab[DIM + j] = b;
}

// ---------------- global mean pool (applies last-layer BN+ReLU) ----------------

__global__ __launch_bounds__(256) void pool_kernel(const float* __restrict__ z,
                                                   const int* __restrict__ gstart,
                                                   const float* __restrict__ ab,
                                                   float* __restrict__ outp) {
    __shared__ float sred[8][DIM];
    const int g = blockIdx.x;
    const int lane = threadIdx.x & 31;
    const int grp = threadIdx.x >> 5;
    const int c4 = lane << 2;
    const int ns = gstart[g], ne = gstart[g + 1];
    float4 a4 = *(const float4*)(ab + c4);
    float4 b4 = *(const float4*)(ab + DIM + c4);
    float4 acc = make_float4(0.f, 0.f, 0.f, 0.f);
    for (int m = ns + grp; m < ne; m += 8) {
        float4 v = *(const float4*)(z + (size_t)m * DIM + c4);
        v = bnrelu4(v, a4, b4);
        acc.x += v.x; acc.y += v.y; acc.z += v.z; acc.w += v.w;
    }
    *(float4*)&sred[grp][c4] = acc;
    __syncthreads();
    if (grp == 0) {
#pragma unroll
        for (int q = 1; q < 8; ++q) {
            float4 u = *(float4*)&sred[q][c4];
            acc.x += u.x; acc.y += u.y; acc.z += u.z; acc.w += u.w;
        }
        float inv = 1.0f / fmaxf((float)(ne - ns), 1.0f);
        float4 o = make_float4(acc.x * inv, acc.y * inv, acc.z * inv, acc.w * inv);
        *(float4*)(outp + (size_t)g * DIM + c4) = o;
    }
}

// ---------------- launcher ----------------

extern "C" void kernel_launch(void* const* d_in, const int* in_sizes, int n_in,
                              void* d_out, int out_size, void* d_ws, size_t ws_size,
                              hipStream_t stream) {
    const float* x     = (const float*)d_in[0];
    const int*   ei    = (const int*)d_in[1];
    const int*   batch = (const int*)d_in[2];
    const float* W1    = (const float*)d_in[3];
    const float* b1    = (const float*)d_in[4];
    const float* W2    = (const float*)d_in[5];
    const float* b2    = (const float*)d_in[6];
    const float* gamma = (const float*)d_in[7];
    const float* beta  = (const float*)d_in[8];
    float* out = (float*)d_out;

    char* ws = (char*)d_ws;
    size_t off = 0;
    auto alloc = [&](size_t bytes) -> void* {
        void* p = ws + off;
        off += (bytes + 255) & ~(size_t)255;
        return p;
    };
    int*   deg      = (int*)alloc((size_t)N_NODESC * 4);
    int*   offs     = (int*)alloc((size_t)(N_NODESC + 1) * 4);
    int*   cursor   = (int*)alloc((size_t)N_NODESC * 4);
    int*   csr      = (int*)alloc((size_t)N_EDGESC * 4);
    int*   gstart   = (int*)alloc((size_t)(N_GRAPHS + 1) * 4);
    float* stats    = (float*)alloc(256 * 4);
    float* ab       = (float*)alloc(256 * 4);
    float* partials = (float*)alloc((size_t)MLP_GRID * 256 * 4);
    float* bufAgg   = (float*)alloc((size_t)N_NODESC * DIM * 4);
    float* bufZ0    = (float*)alloc((size_t)N_NODESC * DIM * 4);
    float* bufZ1    = (float*)alloc((size_t)N_NODESC * DIM * 4);

    const int* srcp = ei;
    const int* dstp = ei + N_EDGESC;

    // CSR build
    hipMemsetAsync(deg, 0, (size_t)N_NODESC * 4, stream);
    hist_kernel<<<(N_EDGESC + 255) / 256, 256, 0, stream>>>(dstp, deg);
    scan_kernel<<<1, 1024, 0, stream>>>(deg, offs);
    hipMemcpyAsync(cursor, offs, (size_t)N_NODESC * 4, hipMemcpyDeviceToDevice, stream);
    fill_kernel<<<(N_EDGESC + 255) / 256, 256, 0, stream>>>(srcp, dstp, cursor, csr);

    // graph boundaries
    ginit_kernel<<<1, 256, 0, stream>>>(gstart);
    gbound_kernel<<<(N_NODESC + 255) / 256, 256, 0, stream>>>(batch, gstart);

    const float* hin = x;
    float* zbufs[2] = {bufZ0, bufZ1};
    for (int l = 0; l < N_LAYERS; ++l) {
        float* zout = zbufs[l & 1];
        const float* W1l = W1 + (size_t)l * DIM * DIM;
        const float* b1l = b1 + (size_t)l * DIM;
        const float* W2l = W2 + (size_t)l * DIM * DIM;
        const float* b2l = b2 + (size_t)l * DIM;
        if (l == 0)
            gather_sliced<0><<<NCHUNK * NSLICE, 256, 0, stream>>>(hin, nullptr, offs, csr, bufAgg);
        else
            gather_sliced<1><<<NCHUNK * NSLICE, 256, 0, stream>>>(hin, ab, offs, csr, bufAgg);
        mlp_persist<<<MLP_GRID, MLP_TPB, MLP_LDS_FLOATS * 4, stream>>>(
            bufAgg, W1l, b1l, W2l, b2l, zout, partials);
        hipMemsetAsync(stats, 0, 256 * 4, stream);
        reduce_stats<<<32, 256, 0, stream>>>(partials, stats);
        bn_finalize<<<1, DIM, 0, stream>>>(stats, gamma + (size_t)l * DIM, beta + (size_t)l * DIM, ab);
        hin = zout;
    }

    pool_kernel<<<N_GRAPHS, 256, 0, stream>>>(hin, gstart, ab, out);
}

// Round 12
// 890.365 us; speedup vs baseline: 3.6509x; 1.3391x over previous
//
#include <hip/hip_runtime.h>

#define N_NODESC 50000
#define N_EDGESC 600000
#define DIM 128
#define N_LAYERS 4
#define N_GRAPHS 128
#define BN_EPSF 1e-5f

// persistent MLP config
#define MLP_GRID 256
#define MLP_TPB 512
#define TROWS 32
#define NTILES ((N_NODESC + TROWS - 1) / TROWS)        // 1563
#define MLP_LDS_FLOATS (16384 + 16384 + TROWS * DIM)   // 36864 floats = 144 KiB
// stats reduce
#define RED_ROWS 8                                     // 256 partial rows / 32 blocks

// gather config
#define GCHUNK 128
#define NCHUNK 391        // ceil(N_NODESC / GCHUNK)
#define NSLICE 8
#define SLICE_COLS 16

// ---------------- CSR build ----------------

__global__ void hist_kernel(const int* __restrict__ dst, int* __restrict__ deg) {
    int e = blockIdx.x * blockDim.x + threadIdx.x;
    if (e < N_EDGESC) atomicAdd(&deg[dst[e]], 1);
}

__global__ void scan_kernel(const int* __restrict__ deg, int* __restrict__ offs) {
    __shared__ int sdata[1024];
    __shared__ int s_carry;
    const int t = threadIdx.x;
    if (t == 0) s_carry = 0;
    __syncthreads();
    for (int base = 0; base < N_NODESC; base += 1024) {
        int i = base + t;
        int v = (i < N_NODESC) ? deg[i] : 0;
        sdata[t] = v;
        __syncthreads();
        int x = v;
        for (int o = 1; o < 1024; o <<= 1) {
            int y = (t >= o) ? sdata[t - o] : 0;
            __syncthreads();
            x += y;
            sdata[t] = x;
            __syncthreads();
        }
        int carry = s_carry;
        if (i < N_NODESC) offs[i] = carry + x - v;   // exclusive
        int total = sdata[1023];
        __syncthreads();
        if (t == 0) s_carry = carry + total;
        __syncthreads();
    }
    if (t == 0) offs[N_NODESC] = s_carry;
}

__global__ void fill_kernel(const int* __restrict__ src, const int* __restrict__ dst,
                            int* __restrict__ cursor, int* __restrict__ csr) {
    int e = blockIdx.x * blockDim.x + threadIdx.x;
    if (e < N_EDGESC) {
        int p = atomicAdd(&cursor[dst[e]], 1);
        csr[p] = src[e];
    }
}

// ---------------- graph boundaries (batch is sorted) ----------------

__global__ void ginit_kernel(int* __restrict__ gstart) {
    int i = threadIdx.x;
    if (i <= N_GRAPHS) gstart[i] = N_NODESC;
}

__global__ void gbound_kernel(const int* __restrict__ batch, int* __restrict__ gstart) {
    int i = blockIdx.x * blockDim.x + threadIdx.x;
    if (i >= N_NODESC) return;
    int b = batch[i];
    int bp = (i == 0) ? -1 : batch[i - 1];
    for (int g = bp + 1; g <= b; ++g) gstart[g] = i;
}

// ---------------- helpers ----------------

__device__ __forceinline__ float4 bnrelu4(float4 v, float4 a, float4 b) {
    float4 r;
    r.x = fmaxf(fmaf(v.x, a.x, b.x), 0.f);
    r.y = fmaxf(fmaf(v.y, a.y, b.y), 0.f);
    r.z = fmaxf(fmaf(v.z, a.z, b.z), 0.f);
    r.w = fmaxf(fmaf(v.w, a.w, b.w), 0.f);
    return r;
}

// ---------------- sliced gather, ILP version ----------------
// slice = blockIdx&7 -> one XCD (round-robin dispatch); per-XCD h-slice = 3.2 MB.
// 16 groups of 16 lanes; each group processes TWO nodes interleaved with the edge
// loop unrolled x4 -> up to 8 independent h-loads in flight per thread (the round-11
// profile showed a serial dependent chain: VALUBusy 13%, 1.9 TB/s on L2-resident data).
// agg writes are non-temporal: slice writes are 64B halves of 128B lines shared with
// the adjacent slice on ANOTHER XCD -> write-allocate RMW; NT store avoids it.

template <int APPLY>
__global__ __launch_bounds__(256) void gather_sliced(const float* __restrict__ hin,
                                                     const float* __restrict__ ab,
                                                     const int* __restrict__ offs,
                                                     const int* __restrict__ csr,
                                                     float* __restrict__ agg) {
    const int slice = blockIdx.x & (NSLICE - 1);
    const int chunk = blockIdx.x >> 3;
    const int t = threadIdx.x;
    const int lane16 = t & 15;
    const int grp = t >> 4;
    const int col = slice * SLICE_COLS + lane16;
    float a = 1.f, b = 0.f;
    if (APPLY) { a = ab[col]; b = ab[DIM + col]; }
    const int nbase = chunk * GCHUNK;

#define BNW(w) (APPLY ? fmaxf(fmaf((w), a, b), 0.f) : (w))

    for (int k = 0; k < GCHUNK; k += 32) {
        const int nodeA = nbase + grp + k;
        const int nodeB = nodeA + 16;
        const bool okA = nodeA < N_NODESC;
        const bool okB = nodeB < N_NODESC;
        float accA = 0.f, accB = 0.f;
        int eA = 0, eA1 = 0, eB = 0, eB1 = 0;
        if (okA) { eA = offs[nodeA]; eA1 = offs[nodeA + 1]; }
        if (okB) { eB = offs[nodeB]; eB1 = offs[nodeB + 1]; }
        if (okA) { float v = hin[(size_t)nodeA * DIM + col]; accA = BNW(v); }
        if (okB) { float v = hin[(size_t)nodeB * DIM + col]; accB = BNW(v); }

        // joint unrolled phase: 8 h-loads in flight
        while (eA + 4 <= eA1 && eB + 4 <= eB1) {
            int sa0 = csr[eA + 0], sa1 = csr[eA + 1], sa2 = csr[eA + 2], sa3 = csr[eA + 3];
            int sb0 = csr[eB + 0], sb1 = csr[eB + 1], sb2 = csr[eB + 2], sb3 = csr[eB + 3];
            float wa0 = hin[(size_t)sa0 * DIM + col];
            float wa1 = hin[(size_t)sa1 * DIM + col];
            float wa2 = hin[(size_t)sa2 * DIM + col];
            float wa3 = hin[(size_t)sa3 * DIM + col];
            float wb0 = hin[(size_t)sb0 * DIM + col];
            float wb1 = hin[(size_t)sb1 * DIM + col];
            float wb2 = hin[(size_t)sb2 * DIM + col];
            float wb3 = hin[(size_t)sb3 * DIM + col];
            accA += BNW(wa0) + BNW(wa1) + BNW(wa2) + BNW(wa3);
            accB += BNW(wb0) + BNW(wb1) + BNW(wb2) + BNW(wb3);
            eA += 4; eB += 4;
        }
        // drain A, unrolled
        while (eA + 4 <= eA1) {
            int s0 = csr[eA + 0], s1 = csr[eA + 1], s2 = csr[eA + 2], s3 = csr[eA + 3];
            float w0 = hin[(size_t)s0 * DIM + col];
            float w1 = hin[(size_t)s1 * DIM + col];
            float w2 = hin[(size_t)s2 * DIM + col];
            float w3 = hin[(size_t)s3 * DIM + col];
            accA += BNW(w0) + BNW(w1) + BNW(w2) + BNW(w3);
            eA += 4;
        }
        // drain B, unrolled
        while (eB + 4 <= eB1) {
            int s0 = csr[eB + 0], s1 = csr[eB + 1], s2 = csr[eB + 2], s3 = csr[eB + 3];
            float w0 = hin[(size_t)s0 * DIM + col];
            float w1 = hin[(size_t)s1 * DIM + col];
            float w2 = hin[(size_t)s2 * DIM + col];
            float w3 = hin[(size_t)s3 * DIM + col];
            accB += BNW(w0) + BNW(w1) + BNW(w2) + BNW(w3);
            eB += 4;
        }
        // scalar tails, pair-interleaved
        while (eA < eA1 && eB < eB1) {
            int s0 = csr[eA++];
            int s1 = csr[eB++];
            float w0 = hin[(size_t)s0 * DIM + col];
            float w1 = hin[(size_t)s1 * DIM + col];
            accA += BNW(w0);
            accB += BNW(w1);
        }
        while (eA < eA1) {
            int s = csr[eA++];
            float w = hin[(size_t)s * DIM + col];
            accA += BNW(w);
        }
        while (eB < eB1) {
            int s = csr[eB++];
            float w = hin[(size_t)s * DIM + col];
            accB += BNW(w);
        }

        if (okA) __builtin_nontemporal_store(accA, &agg[(size_t)nodeA * DIM + col]);
        if (okB) __builtin_nontemporal_store(accB, &agg[(size_t)nodeB * DIM + col]);
    }
#undef BNW
}

// ---------------- persistent weight-resident MLP (unchanged, round-11-verified) ----------------

__global__ __launch_bounds__(MLP_TPB, 2) void mlp_persist(const float* __restrict__ in,
                                                          const float* __restrict__ W1,
                                                          const float* __restrict__ b1,
                                                          const float* __restrict__ W2,
                                                          const float* __restrict__ b2,
                                                          float* __restrict__ zout,
                                                          float* __restrict__ partials) {
    extern __shared__ float lds[];
    float* W1s = lds;                    // [128][128]
    float* W2s = lds + 16384;            // [128][128]
    float* inT = lds + 32768;            // [32][128] (also mid, also reduce scratch)
    const int t = threadIdx.x;

#pragma unroll
    for (int p = 0; p < 8; ++p) {
        int idx = (p * MLP_TPB + t) << 2;
        *(float4*)&W1s[idx] = *(const float4*)(W1 + idx);
        *(float4*)&W2s[idx] = *(const float4*)(W2 + idx);
    }

    const int lane = t & 31;
    const int j4 = lane << 2;
    const int m0 = (t >> 5) << 1;
    const float4 b1v = *(const float4*)(b1 + j4);
    const float4 b2v = *(const float4*)(b2 + j4);
    float s1[4] = {0.f, 0.f, 0.f, 0.f};
    float s2[4] = {0.f, 0.f, 0.f, 0.f};

    __syncthreads();

    for (int tile = blockIdx.x; tile < NTILES; tile += MLP_GRID) {
        const int nodeBase = tile * TROWS;

#pragma unroll
        for (int p = 0; p < 2; ++p) {
            int idx = p * MLP_TPB + t;
            int row = idx >> 5, cc = (idx & 31) << 2;
            int node = nodeBase + row;
            float4 v = make_float4(0.f, 0.f, 0.f, 0.f);
            if (node < N_NODESC) v = *(const float4*)(in + (size_t)node * DIM + cc);
            *(float4*)&inT[row * DIM + cc] = v;
        }
        __syncthreads();

        float acc[2][4];
#pragma unroll
        for (int m = 0; m < 2; ++m)
#pragma unroll
            for (int j = 0; j < 4; ++j) acc[m][j] = 0.f;

#pragma unroll 8
        for (int k = 0; k < DIM; k += 4) {
            float4 w0 = *(float4*)&W1s[(k + 0) * DIM + j4];
            float4 w1 = *(float4*)&W1s[(k + 1) * DIM + j4];
            float4 w2v = *(float4*)&W1s[(k + 2) * DIM + j4];
            float4 w3 = *(float4*)&W1s[(k + 3) * DIM + j4];
#pragma unroll
            for (int m = 0; m < 2; ++m) {
                float4 iv = *(float4*)&inT[(m0 + m) * DIM + k];
                acc[m][0] += iv.x * w0.x + iv.y * w1.x + iv.z * w2v.x + iv.w * w3.x;
                acc[m][1] += iv.x * w0.y + iv.y * w1.y + iv.z * w2v.y + iv.w * w3.y;
                acc[m][2] += iv.x * w0.z + iv.y * w1.z + iv.z * w2v.z + iv.w * w3.z;
                acc[m][3] += iv.x * w0.w + iv.y * w1.w + iv.z * w2v.w + iv.w * w3.w;
            }
        }
        __syncthreads();

#pragma unroll
        for (int m = 0; m < 2; ++m) {
            float4 v;
            v.x = fmaxf(acc[m][0] + b1v.x, 0.f);
            v.y = fmaxf(acc[m][1] + b1v.y, 0.f);
            v.z = fmaxf(acc[m][2] + b1v.z, 0.f);
            v.w = fmaxf(acc[m][3] + b1v.w, 0.f);
            *(float4*)&inT[(m0 + m) * DIM + j4] = v;
            acc[m][0] = acc[m][1] = acc[m][2] = acc[m][3] = 0.f;
        }
        __syncthreads();

#pragma unroll 8
        for (int k = 0; k < DIM; k += 4) {
            float4 w0 = *(float4*)&W2s[(k + 0) * DIM + j4];
            float4 w1 = *(float4*)&W2s[(k + 1) * DIM + j4];
            float4 w2v = *(float4*)&W2s[(k + 2) * DIM + j4];
            float4 w3 = *(float4*)&W2s[(k + 3) * DIM + j4];
#pragma unroll
            for (int m = 0; m < 2; ++m) {
                float4 iv = *(float4*)&inT[(m0 + m) * DIM + k];
                acc[m][0] += iv.x * w0.x + iv.y * w1.x + iv.z * w2v.x + iv.w * w3.x;
                acc[m][1] += iv.x * w0.y + iv.y * w1.y + iv.z * w2v.y + iv.w * w3.y;
                acc[m][2] += iv.x * w0.z + iv.y * w1.z + iv.z * w2v.z + iv.w * w3.z;
                acc[m][3] += iv.x * w0.w + iv.y * w1.w + iv.z * w2v.w + iv.w * w3.w;
            }
        }

#pragma unroll
        for (int m = 0; m < 2; ++m) {
            int node = nodeBase + m0 + m;
            if (node < N_NODESC) {
                float4 z;
                z.x = acc[m][0] + b2v.x;
                z.y = acc[m][1] + b2v.y;
                z.z = acc[m][2] + b2v.z;
                z.w = acc[m][3] + b2v.w;
                *(float4*)(zout + (size_t)node * DIM + j4) = z;
                s1[0] += z.x; s2[0] += z.x * z.x;
                s1[1] += z.y; s2[1] += z.y * z.y;
                s1[2] += z.z; s2[2] += z.z * z.z;
                s1[3] += z.w; s2[3] += z.w * z.w;
            }
        }
        __syncthreads();
    }

    *(float4*)&inT[t * 8 + 0] = make_float4(s1[0], s1[1], s1[2], s1[3]);
    *(float4*)&inT[t * 8 + 4] = make_float4(s2[0], s2[1], s2[2], s2[3]);
    __syncthreads();
    if (t < 32) {
        float4 S1 = make_float4(0.f, 0.f, 0.f, 0.f);
        float4 S2 = make_float4(0.f, 0.f, 0.f, 0.f);
#pragma unroll
        for (int g = 0; g < 16; ++g) {
            float4 u1 = *(float4*)&inT[(g * 32 + t) * 8 + 0];
            float4 u2 = *(float4*)&inT[(g * 32 + t) * 8 + 4];
            S1.x += u1.x; S1.y += u1.y; S1.z += u1.z; S1.w += u1.w;
            S2.x += u2.x; S2.y += u2.y; S2.z += u2.z; S2.w += u2.w;
        }
        *(float4*)(partials + (size_t)blockIdx.x * 256 + t * 4) = S1;
        *(float4*)(partials + (size_t)blockIdx.x * 256 + DIM + t * 4) = S2;
    }
}

// ---------------- stats reduce + BN finalize ----------------

__global__ __launch_bounds__(256) void reduce_stats(const float* __restrict__ partials,
                                                    float* __restrict__ stats) {
    int c = threadIdx.x;
    int r0 = blockIdx.x * RED_ROWS;
    int r1 = r0 + RED_ROWS;
    if (r1 > MLP_GRID) r1 = MLP_GRID;
    float s = 0.f;
    for (int r = r0; r < r1; ++r) s += partials[(size_t)r * 256 + c];
    atomicAdd(&stats[c], s);
}

__global__ void bn_finalize(const float* __restrict__ stats, const float* __restrict__ gamma,
                            const float* __restrict__ beta, float* __restrict__ ab) {
    int j = threadIdx.x;
    float s1 = stats[j], s2 = stats[DIM + j];
    const float invN = 1.0f / (float)N_NODESC;
    float mean = s1 * invN;
    float var = s2 * invN - mean * mean;
    float a = gamma[j] * rsqrtf(var + BN_EPSF);
    float b = beta[j] - mean * a;
    ab[j] = a;
    ab[DIM + j] = b;
}

// ---------------- global mean pool (applies last-layer BN+ReLU) ----------------

__global__ __launch_bounds__(256) void pool_kernel(const float* __restrict__ z,
                                                   const int* __restrict__ gstart,
                                                   const float* __restrict__ ab,
                                                   float* __restrict__ outp) {
    __shared__ float sred[8][DIM];
    const int g = blockIdx.x;
    const int lane = threadIdx.x & 31;
    const int grp = threadIdx.x >> 5;
    const int c4 = lane << 2;
    const int ns = gstart[g], ne = gstart[g + 1];
    float4 a4 = *(const float4*)(ab + c4);
    float4 b4 = *(const float4*)(ab + DIM + c4);
    float4 acc = make_float4(0.f, 0.f, 0.f, 0.f);
    for (int m = ns + grp; m < ne; m += 8) {
        float4 v = *(const float4*)(z + (size_t)m * DIM + c4);
        v = bnrelu4(v, a4, b4);
        acc.x += v.x; acc.y += v.y; acc.z += v.z; acc.w += v.w;
    }
    *(float4*)&sred[grp][c4] = acc;
    __syncthreads();
    if (grp == 0) {
#pragma unroll
        for (int q = 1; q < 8; ++q) {
            float4 u = *(float4*)&sred[q][c4];
            acc.x += u.x; acc.y += u.y; acc.z += u.z; acc.w += u.w;
        }
        float inv = 1.0f / fmaxf((float)(ne - ns), 1.0f);
        float4 o = make_float4(acc.x * inv, acc.y * inv, acc.z * inv, acc.w * inv);
        *(float4*)(outp + (size_t)g * DIM + c4) = o;
    }
}

// ---------------- launcher ----------------

extern "C" void kernel_launch(void* const* d_in, const int* in_sizes, int n_in,
                              void* d_out, int out_size, void* d_ws, size_t ws_size,
                              hipStream_t stream) {
    const float* x     = (const float*)d_in[0];
    const int*   ei    = (const int*)d_in[1];
    const int*   batch = (const int*)d_in[2];
    const float* W1    = (const float*)d_in[3];
    const float* b1    = (const float*)d_in[4];
    const float* W2    = (const float*)d_in[5];
    const float* b2    = (const float*)d_in[6];
    const float* gamma = (const float*)d_in[7];
    const float* beta  = (const float*)d_in[8];
    float* out = (float*)d_out;

    char* ws = (char*)d_ws;
    size_t off = 0;
    auto alloc = [&](size_t bytes) -> void* {
        void* p = ws + off;
        off += (bytes + 255) & ~(size_t)255;
        return p;
    };
    int*   deg      = (int*)alloc((size_t)N_NODESC * 4);
    int*   offs     = (int*)alloc((size_t)(N_NODESC + 1) * 4);
    int*   cursor   = (int*)alloc((size_t)N_NODESC * 4);
    int*   csr      = (int*)alloc((size_t)N_EDGESC * 4);
    int*   gstart   = (int*)alloc((size_t)(N_GRAPHS + 1) * 4);
    float* stats    = (float*)alloc(256 * 4);
    float* ab       = (float*)alloc(256 * 4);
    float* partials = (float*)alloc((size_t)MLP_GRID * 256 * 4);
    float* bufAgg   = (float*)alloc((size_t)N_NODESC * DIM * 4);
    float* bufZ0    = (float*)alloc((size_t)N_NODESC * DIM * 4);
    float* bufZ1    = (float*)alloc((size_t)N_NODESC * DIM * 4);

    const int* srcp = ei;
    const int* dstp = ei + N_EDGESC;

    // CSR build
    hipMemsetAsync(deg, 0, (size_t)N_NODESC * 4, stream);
    hist_kernel<<<(N_EDGESC + 255) / 256, 256, 0, stream>>>(dstp, deg);
    scan_kernel<<<1, 1024, 0, stream>>>(deg, offs);
    hipMemcpyAsync(cursor, offs, (size_t)N_NODESC * 4, hipMemcpyDeviceToDevice, stream);
    fill_kernel<<<(N_EDGESC + 255) / 256, 256, 0, stream>>>(srcp, dstp, cursor, csr);

    // graph boundaries
    ginit_kernel<<<1, 256, 0, stream>>>(gstart);
    gbound_kernel<<<(N_NODESC + 255) / 256, 256, 0, stream>>>(batch, gstart);

    const float* hin = x;
    float* zbufs[2] = {bufZ0, bufZ1};
    for (int l = 0; l < N_LAYERS; ++l) {
        float* zout = zbufs[l & 1];
        const float* W1l = W1 + (size_t)l * DIM * DIM;
        const float* b1l = b1 + (size_t)l * DIM;
        const float* W2l = W2 + (size_t)l * DIM * DIM;
        const float* b2l = b2 + (size_t)l * DIM;
        if (l == 0)
            gather_sliced<0><<<NCHUNK * NSLICE, 256, 0, stream>>>(hin, nullptr, offs, csr, bufAgg);
        else
            gather_sliced<1><<<NCHUNK * NSLICE, 256, 0, stream>>>(hin, ab, offs, csr, bufAgg);
        mlp_persist<<<MLP_GRID, MLP_TPB, MLP_LDS_FLOATS * 4, stream>>>(
            bufAgg, W1l, b1l, W2l, b2l, zout, partials);
        hipMemsetAsync(stats, 0, 256 * 4, stream);
        reduce_stats<<<32, 256, 0, stream>>>(partials, stats);
        bn_finalize<<<1, DIM, 0, stream>>>(stats, gamma + (size_t)l * DIM, beta + (size_t)l * DIM, ab);
        hin = zout;
    }

    pool_kernel<<<N_GRAPHS, 256, 0, stream>>>(hin, gstart, ab, out);
}